// Round 3
// baseline (423.931 us; speedup 1.0000x reference)
//
#include <hip/hip_runtime.h>
#include <stdint.h>

#define B_N 4096
#define T_N 17
#define C_N 512
#define KTOT 1024   // K = [x | trend] = 2*C_N

typedef __bf16 bf16x8 __attribute__((ext_vector_type(8)));
typedef float  f32x4  __attribute__((ext_vector_type(4)));

// fp32 -> bf16 round-to-nearest-even (finite inputs)
__device__ __forceinline__ unsigned short f2b(float f){
  unsigned u = __float_as_uint(f);
  return (unsigned short)((u + 0x7fffu + ((u >> 16) & 1u)) >> 16);
}
__device__ __forceinline__ unsigned pk2(float a, float b){
  return (unsigned)f2b(a) | ((unsigned)f2b(b) << 16);
}

// async global->LDS, 16B/lane. LDS dest is wave-uniform base + lane*16; our
// per-lane dest addresses are exactly that (chunk ids are lane-consecutive).
__device__ __forceinline__ void gll16(const void* g, void* l){
  __builtin_amdgcn_global_load_lds(
      (const __attribute__((address_space(1))) unsigned int*)g,
      (__attribute__((address_space(3))) unsigned int*)l, 16, 0, 0);
}

#define BAR()   __builtin_amdgcn_s_barrier()
#define VMC(n)  do{ asm volatile("s_waitcnt vmcnt(" #n ")" ::: "memory"); \
                    __builtin_amdgcn_sched_barrier(0); }while(0)
#define FENCE() asm volatile("" ::: "memory")

// ---------------------------------------------------------------------------
// prep_w: Wcat[t][d][0:512] = bf16(Ws), [512:1024] = bf16(Wt - Ws)
// ---------------------------------------------------------------------------
__global__ __launch_bounds__(256) void prep_w(
    const float* __restrict__ Ws, const float* __restrict__ Wt,
    unsigned short* __restrict__ wcat)
{
  const size_t i8 = ((size_t)blockIdx.x * 256 + threadIdx.x) * 8;
  const int t   = (int)(i8 >> 18);          // / (512*512)
  const int rem = (int)(i8 & 262143);
  const int d   = rem >> 9;
  const int c   = rem & 511;
  float4 a0 = *(const float4*)(Ws + i8);
  float4 a1 = *(const float4*)(Ws + i8 + 4);
  float4 b0 = *(const float4*)(Wt + i8);
  float4 b1 = *(const float4*)(Wt + i8 + 4);
  uint4 oa, od;
  oa.x = pk2(a0.x, a0.y); oa.y = pk2(a0.z, a0.w);
  oa.z = pk2(a1.x, a1.y); oa.w = pk2(a1.z, a1.w);
  od.x = pk2(b0.x - a0.x, b0.y - a0.y); od.y = pk2(b0.z - a0.z, b0.w - a0.w);
  od.z = pk2(b1.x - a1.x, b1.y - a1.y); od.w = pk2(b1.z - a1.z, b1.w - a1.w);
  unsigned short* base = wcat + ((size_t)(t * C_N + d)) * KTOT + c;
  *(uint4*)base = oa;
  *(uint4*)(base + C_N) = od;
}

__global__ __launch_bounds__(256) void prep_bsum(
    const float* __restrict__ bs, const float* __restrict__ bt, float* __restrict__ o)
{
  const int i = blockIdx.x * 256 + threadIdx.x;
  o[i] = bs[i] + bt[i];
}

// ---------------------------------------------------------------------------
// prep_a: one pass over x. Acat[t][b][0:512] = bf16(x[b,t,:]),
//         Acat[t][b][512:1024] = bf16(trend[b,t,:]) with trend = u + t*v,
//         u = (S + 18*x0 + 2*x16)/37, v = (x16 - x0)/37.
// ---------------------------------------------------------------------------
__global__ __launch_bounds__(256) void prep_a(
    const float* __restrict__ x, unsigned short* __restrict__ acat)
{
  const int idx = blockIdx.x * 256 + threadIdx.x;   // 4096 * 64 = 262144
  const int b = idx >> 6;
  const int c = (idx & 63) << 3;
  const float* xp = x + (size_t)b * (T_N * C_N) + c;
  float s[8] = {0,0,0,0,0,0,0,0};
  float f0[8], fl[8];
#pragma unroll
  for (int tt = 0; tt < T_N; ++tt){
    float4 w0 = *(const float4*)(xp + (size_t)tt * C_N);
    float4 w1 = *(const float4*)(xp + (size_t)tt * C_N + 4);
    float f[8] = {w0.x, w0.y, w0.z, w0.w, w1.x, w1.y, w1.z, w1.w};
    uint4 o;
    o.x = pk2(f[0],f[1]); o.y = pk2(f[2],f[3]);
    o.z = pk2(f[4],f[5]); o.w = pk2(f[6],f[7]);
    *(uint4*)(acat + ((size_t)tt * B_N + b) * KTOT + c) = o;
    if (tt == 0){
#pragma unroll
      for (int i=0;i<8;++i) f0[i] = f[i];
    }
    if (tt == T_N-1){
#pragma unroll
      for (int i=0;i<8;++i) fl[i] = f[i];
    }
#pragma unroll
    for (int i=0;i<8;++i) s[i] += f[i];
  }
  const float inv = 1.0f / 37.0f;
  float uu[8], vv[8];
#pragma unroll
  for (int i=0;i<8;++i){
    uu[i] = (s[i] + 18.0f * f0[i] + 2.0f * fl[i]) * inv;
    vv[i] = (fl[i] - f0[i]) * inv;
  }
#pragma unroll
  for (int tt = 0; tt < T_N; ++tt){
    const float tfv = (float)tt;
    float tr[8];
#pragma unroll
    for (int i=0;i<8;++i) tr[i] = fmaf(tfv, vv[i], uu[i]);
    uint4 o;
    o.x = pk2(tr[0],tr[1]); o.y = pk2(tr[2],tr[3]);
    o.z = pk2(tr[4],tr[5]); o.w = pk2(tr[6],tr[7]);
    *(uint4*)(acat + ((size_t)tt * B_N + b) * KTOT + C_N + c) = o;
  }
}

// ---------------------------------------------------------------------------
// gemm8: per token t, out[:,t,:] = Acat[t] (4096x1024) * Wcat[t]^T (512x1024)
//        + bsum[t], fp32 store.
// 256x256 tile, BK=64, 8 waves (2M x 4N), mfma_f32_16x16x32_bf16.
// K-loop: 2 barriers per K-tile. Within a K-tile all 24 ds_read_b128 and
// 64 MFMAs sit in one barrier-free region -> the compiler's fine-grained
// lgkmcnt scheduling overlaps LDS reads with MFMA (within-wave), and waves
// drift freely (cross-wave read/MFMA overlap). Barriers only at the two real
// hazard points: (1) before staging into the buffer just read (WAR),
// (2) after counted VMC(8) so every wave's next-tile loads are landed.
// LDS XOR-swizzle unchanged: chunk cc of row r holds global chunk cc^(r&7);
// global source pre-swizzled so the LDS dest stays linear for global_load_lds.
// ---------------------------------------------------------------------------
__global__ __launch_bounds__(512, 2) void gemm8(
    const unsigned short* __restrict__ acat,
    const unsigned short* __restrict__ wcat,
    const float* __restrict__ bsum,
    float* __restrict__ out)
{
  __shared__ alignas(16) unsigned short A_lds[2][256][64];
  __shared__ alignas(16) unsigned short B_lds[2][256][64];

  const int tid = threadIdx.x;
  const int bid = blockIdx.x;
  // XCD-contiguous swizzle: 544 blocks = 8 XCDs * 68 (exact -> bijective)
  const int wg = (bid & 7) * 68 + (bid >> 3);
  const int t  = wg >> 5;            // 17 tokens * 32 tiles
  const int mt = (wg >> 1) & 15;     // 16 M-tiles of 256
  const int nt = wg & 1;             // 2 N-tiles of 256
  const int m0 = mt << 8;
  const int n0 = nt << 8;

  const int lane = tid & 63;
  const int wave = tid >> 6;
  const int wr = wave >> 2;          // 0..1 : wave row  (128 M rows each)
  const int wc = wave & 3;           // 0..3 : wave col  (64 N cols each)
  const int lr = lane & 15;
  const int g  = lane >> 4;          // k-chunk group 0..3

  // ---- staging bases: chunk c = r*512 + tid; row = c>>3; cc = c&7.
  const int row0 = tid >> 3;               // 0..63
  const int cc0  = tid & 7;
  const int cswz = ((cc0 ^ (row0 & 7)) << 3);   // inverse-swizzled src col (ush)
  const unsigned short* gA0 = acat + ((size_t)t * B_N + m0 + row0) * KTOT + cswz;
  const unsigned short* gB0 = wcat + ((size_t)t * C_N + n0 + row0) * KTOT + cswz;
  unsigned short* lA0 = &A_lds[0][row0][cc0 << 3];
  unsigned short* lB0 = &B_lds[0][row0][cc0 << 3];

  auto stageA = [&](int bb, int kt){
#pragma unroll
    for (int r = 0; r < 4; ++r)            // rows r*64+row0, dest = tid*16B linear
      gll16(gA0 + (size_t)kt * 64 + r * 65536, lA0 + bb * 16384 + r * 4096);
  };
  auto stageB = [&](int bb, int kt){
#pragma unroll
    for (int r = 0; r < 4; ++r)
      gll16(gB0 + (size_t)kt * 64 + r * 65536, lB0 + bb * 16384 + r * 4096);
  };

  // ---- fragment-read bases (swizzled): row = {wr*128|wc*64} + fragrow*16 + lr,
  // chunk for k-step ks, group g is (ks*4+g) ^ (row&7); row&7 == lr&7.
  const int sw  = lr & 7;
  const int ca0 = (( g     ) ^ sw) << 3;   // ks0 chunk offset (ush)
  const int ca1 = ((4 | g  ) ^ sw) << 3;   // ks1 chunk offset (ush)
  const unsigned short* Arow = &A_lds[0][wr * 128 + lr][0];
  const unsigned short* Brow = &B_lds[0][wc * 64  + lr][0];

  f32x4 acc[8][4];
#pragma unroll
  for (int i=0;i<8;++i)
#pragma unroll
    for (int j=0;j<4;++j){ f32x4 z = {0.f,0.f,0.f,0.f}; acc[i][j] = z; }

  auto rdA4 = [&](bf16x8 (&dst)[4][2], int bb, int mih){
    const unsigned short* p = Arow + bb * 16384 + mih * 1024;
#pragma unroll
    for (int mi=0;mi<4;++mi){
      dst[mi][0] = *(const bf16x8*)(p + mi * 1024 + ca0);
      dst[mi][1] = *(const bf16x8*)(p + mi * 1024 + ca1);
    }
  };
  auto rdB2 = [&](bf16x8 (&dst)[2][2], int bb, int nih){
    const unsigned short* p = Brow + bb * 16384 + nih * 1024;
#pragma unroll
    for (int ni=0;ni<2;++ni){
      dst[ni][0] = *(const bf16x8*)(p + ni * 1024 + ca0);
      dst[ni][1] = *(const bf16x8*)(p + ni * 1024 + ca1);
    }
  };

  // ---- prologue: K-tiles 0 -> buf0, 1 -> buf1 (16 loads); force kt0 landed.
  stageB(0, 0); stageA(0, 0);
  stageB(1, 1); stageA(1, 1);
  VMC(8);
  BAR();

#pragma unroll 1
  for (int it = 0; it < 16; ++it){
    const int bb = it & 1;
    bf16x8 b01[2][2], b23[2][2], aL[4][2], aH[4][2];

    // one barrier-free region: 24 ds_reads + 64 MFMAs, compiler-interleaved
    rdB2(b01, bb, 0);
    rdB2(b23, bb, 2);
    rdA4(aL, bb, 0);

    __builtin_amdgcn_s_setprio(1);
#pragma unroll
    for (int mi=0;mi<4;++mi){
      if (mi == 2) rdA4(aH, bb, 4);        // inject aH reads mid-cluster
#pragma unroll
      for (int ni=0;ni<2;++ni){
        acc[mi][ni]   = __builtin_amdgcn_mfma_f32_16x16x32_bf16(aL[mi][0], b01[ni][0], acc[mi][ni],0,0,0);
        acc[mi][ni]   = __builtin_amdgcn_mfma_f32_16x16x32_bf16(aL[mi][1], b01[ni][1], acc[mi][ni],0,0,0);
        acc[mi][2+ni] = __builtin_amdgcn_mfma_f32_16x16x32_bf16(aL[mi][0], b23[ni][0], acc[mi][2+ni],0,0,0);
        acc[mi][2+ni] = __builtin_amdgcn_mfma_f32_16x16x32_bf16(aL[mi][1], b23[ni][1], acc[mi][2+ni],0,0,0);
      }
    }
#pragma unroll
    for (int mi=0;mi<4;++mi){
#pragma unroll
      for (int ni=0;ni<2;++ni){
        acc[4+mi][ni]   = __builtin_amdgcn_mfma_f32_16x16x32_bf16(aH[mi][0], b01[ni][0], acc[4+mi][ni],0,0,0);
        acc[4+mi][ni]   = __builtin_amdgcn_mfma_f32_16x16x32_bf16(aH[mi][1], b01[ni][1], acc[4+mi][ni],0,0,0);
        acc[4+mi][2+ni] = __builtin_amdgcn_mfma_f32_16x16x32_bf16(aH[mi][0], b23[ni][0], acc[4+mi][2+ni],0,0,0);
        acc[4+mi][2+ni] = __builtin_amdgcn_mfma_f32_16x16x32_bf16(aH[mi][1], b23[ni][1], acc[4+mi][2+ni],0,0,0);
      }
    }
    __builtin_amdgcn_s_setprio(0);

    FENCE();
    BAR();                                 // all waves done reading buf bb
    if (it < 14){
      stageB(bb, it + 2);                  // overwrite buf bb with K-tile it+2
      stageA(bb, it + 2);
      VMC(8);                              // K-tile it+1 (for next iter) landed
    } else if (it == 14){
      VMC(0);                              // K-tile 15 landed
    }
    BAR();                                 // every wave's portion landed
  }

  // ---- epilogue: C/D frag: col = lane&15 -> n, row = (lane>>4)*4 + reg -> m
  float bias[4];
#pragma unroll
  for (int ni=0;ni<4;++ni)
    bias[ni] = bsum[(size_t)t * C_N + n0 + wc*64 + ni*16 + lr];

#pragma unroll
  for (int mi=0;mi<8;++mi){
#pragma unroll
    for (int rr=0;rr<4;++rr){
      const int m = m0 + wr*128 + mi*16 + g*4 + rr;
      float* op = out + ((size_t)m * T_N + t) * C_N + n0 + wc*64 + lr;
#pragma unroll
      for (int ni=0;ni<4;++ni)
        op[ni*16] = acc[mi][ni][rr] + bias[ni];
    }
  }
}

extern "C" void kernel_launch(void* const* d_in, const int* in_sizes, int n_in,
                              void* d_out, int out_size, void* d_ws, size_t ws_size,
                              hipStream_t stream)
{
  const float* x   = (const float*)d_in[0];
  const float* Wsl = (const float*)d_in[1];
  const float* bsl = (const float*)d_in[2];
  const float* Wtr = (const float*)d_in[3];
  const float* btr = (const float*)d_in[4];
  float* out = (float*)d_out;

  const size_t WCAT_BYTES = (size_t)T_N * C_N * KTOT * 2;  // 17,825,792
  const size_t BS_BYTES   = (size_t)T_N * C_N * 4;         // 34,816
  char* ws = (char*)d_ws;
  unsigned short* wcat = (unsigned short*)ws;
  float*          bsum = (float*)(ws + WCAT_BYTES);
  unsigned short* acat = (unsigned short*)(ws + WCAT_BYTES + BS_BYTES);

  prep_w  <<<dim3(2176), dim3(256), 0, stream>>>(Wsl, Wtr, wcat);
  prep_bsum<<<dim3(34),  dim3(256), 0, stream>>>(bsl, btr, bsum);
  prep_a  <<<dim3(1024), dim3(256), 0, stream>>>(x, acat);
  gemm8   <<<dim3(544),  dim3(512), 0, stream>>>(acat, wcat, bsum, out);
  (void)in_sizes; (void)n_in; (void)out_size; (void)ws_size;
}

// Round 4
// 413.361 us; speedup vs baseline: 1.0256x; 1.0256x over previous
//
#include <hip/hip_runtime.h>
#include <stdint.h>

#define B_N 4096
#define T_N 17
#define C_N 512
#define KTOT 1024   // K = [x | trend] = 2*C_N

typedef __bf16 bf16x8 __attribute__((ext_vector_type(8)));
typedef float  f32x4  __attribute__((ext_vector_type(4)));

// fp32 -> bf16 round-to-nearest-even (finite inputs)
__device__ __forceinline__ unsigned short f2b(float f){
  unsigned u = __float_as_uint(f);
  return (unsigned short)((u + 0x7fffu + ((u >> 16) & 1u)) >> 16);
}
__device__ __forceinline__ unsigned pk2(float a, float b){
  return (unsigned)f2b(a) | ((unsigned)f2b(b) << 16);
}

// async global->LDS, 16B/lane; LDS dest = wave-uniform base + lane*16 (our
// per-lane dests are exactly that: chunk ids are lane-consecutive).
__device__ __forceinline__ void gll16(const void* g, void* l){
  __builtin_amdgcn_global_load_lds(
      (const __attribute__((address_space(1))) unsigned int*)g,
      (__attribute__((address_space(3))) unsigned int*)l, 16, 0, 0);
}

#define BAR()   __builtin_amdgcn_s_barrier()
#define VMC(n)  do{ asm volatile("s_waitcnt vmcnt(" #n ")" ::: "memory"); \
                    __builtin_amdgcn_sched_barrier(0); }while(0)
#define FENCE() asm volatile("" ::: "memory")

// ---------------------------------------------------------------------------
// prep_w: Wcat[t][d][0:512] = bf16(Ws), [512:1024] = bf16(Wt - Ws)
// ---------------------------------------------------------------------------
__global__ __launch_bounds__(256) void prep_w(
    const float* __restrict__ Ws, const float* __restrict__ Wt,
    unsigned short* __restrict__ wcat)
{
  const size_t i8 = ((size_t)blockIdx.x * 256 + threadIdx.x) * 8;
  const int t   = (int)(i8 >> 18);          // / (512*512)
  const int rem = (int)(i8 & 262143);
  const int d   = rem >> 9;
  const int c   = rem & 511;
  float4 a0 = *(const float4*)(Ws + i8);
  float4 a1 = *(const float4*)(Ws + i8 + 4);
  float4 b0 = *(const float4*)(Wt + i8);
  float4 b1 = *(const float4*)(Wt + i8 + 4);
  uint4 oa, od;
  oa.x = pk2(a0.x, a0.y); oa.y = pk2(a0.z, a0.w);
  oa.z = pk2(a1.x, a1.y); oa.w = pk2(a1.z, a1.w);
  od.x = pk2(b0.x - a0.x, b0.y - a0.y); od.y = pk2(b0.z - a0.z, b0.w - a0.w);
  od.z = pk2(b1.x - a1.x, b1.y - a1.y); od.w = pk2(b1.z - a1.z, b1.w - a1.w);
  unsigned short* base = wcat + ((size_t)(t * C_N + d)) * KTOT + c;
  *(uint4*)base = oa;
  *(uint4*)(base + C_N) = od;
}

// ---------------------------------------------------------------------------
// prep_a: one pass over x. Acat[t][b][0:512] = bf16(x[b,t,:]),
//         Acat[t][b][512:1024] = bf16(trend[b,t,:]) with trend = u + t*v,
//         u = (S + 18*x0 + 2*x16)/37, v = (x16 - x0)/37.
// ---------------------------------------------------------------------------
__global__ __launch_bounds__(256) void prep_a(
    const float* __restrict__ x, unsigned short* __restrict__ acat)
{
  const int idx = blockIdx.x * 256 + threadIdx.x;   // 4096 * 64 = 262144
  const int b = idx >> 6;
  const int c = (idx & 63) << 3;
  const float* xp = x + (size_t)b * (T_N * C_N) + c;
  float s[8] = {0,0,0,0,0,0,0,0};
  float f0[8], fl[8];
#pragma unroll
  for (int tt = 0; tt < T_N; ++tt){
    float4 w0 = *(const float4*)(xp + (size_t)tt * C_N);
    float4 w1 = *(const float4*)(xp + (size_t)tt * C_N + 4);
    float f[8] = {w0.x, w0.y, w0.z, w0.w, w1.x, w1.y, w1.z, w1.w};
    uint4 o;
    o.x = pk2(f[0],f[1]); o.y = pk2(f[2],f[3]);
    o.z = pk2(f[4],f[5]); o.w = pk2(f[6],f[7]);
    *(uint4*)(acat + ((size_t)tt * B_N + b) * KTOT + c) = o;
    if (tt == 0){
#pragma unroll
      for (int i=0;i<8;++i) f0[i] = f[i];
    }
    if (tt == T_N-1){
#pragma unroll
      for (int i=0;i<8;++i) fl[i] = f[i];
    }
#pragma unroll
    for (int i=0;i<8;++i) s[i] += f[i];
  }
  const float inv = 1.0f / 37.0f;
  float uu[8], vv[8];
#pragma unroll
  for (int i=0;i<8;++i){
    uu[i] = (s[i] + 18.0f * f0[i] + 2.0f * fl[i]) * inv;
    vv[i] = (fl[i] - f0[i]) * inv;
  }
#pragma unroll
  for (int tt = 0; tt < T_N; ++tt){
    const float tfv = (float)tt;
    float tr[8];
#pragma unroll
    for (int i=0;i<8;++i) tr[i] = fmaf(tfv, vv[i], uu[i]);
    uint4 o;
    o.x = pk2(tr[0],tr[1]); o.y = pk2(tr[2],tr[3]);
    o.z = pk2(tr[4],tr[5]); o.w = pk2(tr[6],tr[7]);
    *(uint4*)(acat + ((size_t)tt * B_N + b) * KTOT + C_N + c) = o;
  }
}

// ---------------------------------------------------------------------------
// gemm4: per token t, out[:,t,:] = Acat[t] (4096x1024) * Wcat[t]^T (512x1024)
//        + (bs+bt)[t], fp32 store.
// 128x128 tile, BK=64, 4 waves (2M x 2N, wave tile 64x64), 64 KiB LDS
// -> 2 blocks/CU co-resident: when one block stalls on barrier/vmcnt, the
// other block's waves fill the CU (m97/m114 mechanism). Simple 2-barrier
// K-loop + counted VMC(8) dbuf staging; XOR-swizzled LDS (chunk cc of row r
// holds global chunk cc^(r&7); global src pre-swizzled so LDS dest stays
// linear for global_load_lds). Grid 2176 = 8 XCD x 272 (bijective swizzle).
// ---------------------------------------------------------------------------
__global__ __launch_bounds__(256, 2) void gemm4(
    const unsigned short* __restrict__ acat,
    const unsigned short* __restrict__ wcat,
    const float* __restrict__ bs,
    const float* __restrict__ bt,
    float* __restrict__ out)
{
  __shared__ alignas(16) unsigned short A_lds[2][128][64];   // 32 KiB
  __shared__ alignas(16) unsigned short B_lds[2][128][64];   // 32 KiB

  const int tid = threadIdx.x;
  const int bid = blockIdx.x;
  // XCD-contiguous swizzle: 2176 blocks = 8 XCDs * 272 (exact -> bijective)
  const int wg = (bid & 7) * 272 + (bid >> 3);
  const int t  = wg >> 7;            // 17 tokens * 128 tiles (32 mt x 4 nt)
  const int rm = wg & 127;
  const int mt = rm >> 2;            // 0..31  (consecutive wg share t,mt -> A L2 reuse)
  const int nt = rm & 3;             // 0..3
  const int m0 = mt << 7;
  const int n0 = nt << 7;

  const int lane = tid & 63;
  const int wave = tid >> 6;
  const int wr = wave >> 1;          // 0..1 : 64 M rows each
  const int wc = wave & 1;           // 0..1 : 64 N cols each
  const int lr = lane & 15;
  const int g  = lane >> 4;          // k-chunk group 0..3

  // ---- staging: chunk c = r*256 + tid; row = c>>3 (= r*32 + tid>>3); cc = c&7.
  const int row0 = tid >> 3;               // 0..31
  const int cc0  = tid & 7;
  const int cswz = ((cc0 ^ (row0 & 7)) << 3);   // inverse-swizzled src col (ush)
  const unsigned short* gA0 = acat + ((size_t)t * B_N + m0 + row0) * KTOT + cswz;
  const unsigned short* gB0 = wcat + ((size_t)t * C_N + n0 + row0) * KTOT + cswz;
  unsigned short* lA0 = &A_lds[0][0][0] + tid * 8;
  unsigned short* lB0 = &B_lds[0][0][0] + tid * 8;

  auto stage = [&](int bb, int kt){
#pragma unroll
    for (int r = 0; r < 4; ++r)            // B rows r*32+row0
      gll16(gB0 + (size_t)kt * 64 + r * 32768, lB0 + bb * 8192 + r * 2048);
#pragma unroll
    for (int r = 0; r < 4; ++r)            // A rows r*32+row0
      gll16(gA0 + (size_t)kt * 64 + r * 32768, lA0 + bb * 8192 + r * 2048);
  };

  // ---- fragment reads (swizzled): frag row = {wr|wc}*64 + mi*16 + lr;
  // row&7 == lr&7; chunk for k-step ks, group g = (ks*4+g) ^ (lr&7).
  const int sw  = lr & 7;
  const int ca0 = (( g    ) ^ sw) << 3;    // ks0 chunk offset (ush)
  const int ca1 = ((4 | g ) ^ sw) << 3;    // ks1 chunk offset (ush)
  const unsigned short* Arow = &A_lds[0][wr * 64 + lr][0];
  const unsigned short* Brow = &B_lds[0][wc * 64 + lr][0];

  f32x4 acc[4][4];
#pragma unroll
  for (int i=0;i<4;++i)
#pragma unroll
    for (int j=0;j<4;++j){ f32x4 z = {0.f,0.f,0.f,0.f}; acc[i][j] = z; }

  // ---- prologue: K-tiles 0 -> buf0, 1 -> buf1; force tile0 landed.
  stage(0, 0);
  stage(1, 1);
  VMC(8);
  BAR();

#pragma unroll 1
  for (int it = 0; it < 16; ++it){
    const int bb = it & 1;
    bf16x8 af[4][2], bf[4][2];
#pragma unroll
    for (int i=0;i<4;++i){
      const unsigned short* pB = Brow + bb * 8192 + i * 1024;
      bf[i][0] = *(const bf16x8*)(pB + ca0);
      bf[i][1] = *(const bf16x8*)(pB + ca1);
    }
#pragma unroll
    for (int i=0;i<4;++i){
      const unsigned short* pA = Arow + bb * 8192 + i * 1024;
      af[i][0] = *(const bf16x8*)(pA + ca0);
      af[i][1] = *(const bf16x8*)(pA + ca1);
    }

    __builtin_amdgcn_s_setprio(1);
#pragma unroll
    for (int mi=0;mi<4;++mi)
#pragma unroll
      for (int ni=0;ni<4;++ni){
        acc[mi][ni] = __builtin_amdgcn_mfma_f32_16x16x32_bf16(af[mi][0], bf[ni][0], acc[mi][ni],0,0,0);
        acc[mi][ni] = __builtin_amdgcn_mfma_f32_16x16x32_bf16(af[mi][1], bf[ni][1], acc[mi][ni],0,0,0);
      }
    __builtin_amdgcn_s_setprio(0);

    FENCE();
    BAR();                                 // all waves done reading buf bb
    if (it < 14){
      stage(bb, it + 2);                   // overwrite buf bb with K-tile it+2
      VMC(8);                              // tile it+1 (next iter) landed
    } else if (it == 14){
      VMC(0);                              // tile 15 landed
    }
    BAR();
  }

  // ---- epilogue: bias fused (bs+bt); C/D: col=lane&15 -> n, row=(lane>>4)*4+reg -> m
  float bias[4];
#pragma unroll
  for (int ni=0;ni<4;++ni){
    const size_t bi = (size_t)t * C_N + n0 + wc*64 + ni*16 + lr;
    bias[ni] = bs[bi] + bt[bi];
  }

#pragma unroll
  for (int mi=0;mi<4;++mi){
#pragma unroll
    for (int rr=0;rr<4;++rr){
      const int m = m0 + wr*64 + mi*16 + g*4 + rr;
      float* op = out + ((size_t)m * T_N + t) * C_N + n0 + wc*64 + lr;
#pragma unroll
      for (int ni=0;ni<4;++ni)
        op[ni*16] = acc[mi][ni][rr] + bias[ni];
    }
  }
}

extern "C" void kernel_launch(void* const* d_in, const int* in_sizes, int n_in,
                              void* d_out, int out_size, void* d_ws, size_t ws_size,
                              hipStream_t stream)
{
  const float* x   = (const float*)d_in[0];
  const float* Wsl = (const float*)d_in[1];
  const float* bsl = (const float*)d_in[2];
  const float* Wtr = (const float*)d_in[3];
  const float* btr = (const float*)d_in[4];
  float* out = (float*)d_out;

  const size_t WCAT_BYTES = (size_t)T_N * C_N * KTOT * 2;  // 17,825,792
  char* ws = (char*)d_ws;
  unsigned short* wcat = (unsigned short*)ws;
  unsigned short* acat = (unsigned short*)(ws + WCAT_BYTES);

  prep_w <<<dim3(2176), dim3(256), 0, stream>>>(Wsl, Wtr, wcat);
  prep_a <<<dim3(1024), dim3(256), 0, stream>>>(x, acat);
  gemm4  <<<dim3(2176), dim3(256), 0, stream>>>(acat, wcat, bsl, btr, out);
  (void)in_sizes; (void)n_in; (void)out_size; (void)ws_size;
}

// Round 5
// 405.254 us; speedup vs baseline: 1.0461x; 1.0200x over previous
//
#include <hip/hip_runtime.h>
#include <stdint.h>

#define B_N 4096
#define T_N 17
#define C_N 512
#define KTOT 1024   // K = [x | trend] = 2*C_N

typedef __bf16 bf16x8 __attribute__((ext_vector_type(8)));
typedef float  f32x4  __attribute__((ext_vector_type(4)));

// fp32 -> bf16 round-to-nearest-even (finite inputs)
__device__ __forceinline__ unsigned short f2b(float f){
  unsigned u = __float_as_uint(f);
  return (unsigned short)((u + 0x7fffu + ((u >> 16) & 1u)) >> 16);
}
__device__ __forceinline__ unsigned pk2(float a, float b){
  return (unsigned)f2b(a) | ((unsigned)f2b(b) << 16);
}

// async global->LDS, 16B/lane; LDS dest = wave-uniform base + lane*16 (our
// per-lane dests are exactly that: chunk ids are lane-consecutive).
__device__ __forceinline__ void gll16(const void* g, void* l){
  __builtin_amdgcn_global_load_lds(
      (const __attribute__((address_space(1))) unsigned int*)g,
      (__attribute__((address_space(3))) unsigned int*)l, 16, 0, 0);
}

#define BAR()   __builtin_amdgcn_s_barrier()
#define LGKM0() do{ asm volatile("s_waitcnt lgkmcnt(0)" ::: "memory"); \
                    __builtin_amdgcn_sched_barrier(0); }while(0)
#define VMC(n)  do{ asm volatile("s_waitcnt vmcnt(" #n ")" ::: "memory"); \
                    __builtin_amdgcn_sched_barrier(0); }while(0)

// ---------------------------------------------------------------------------
// prep_w: Wcat[t][d][0:512] = bf16(Ws), [512:1024] = bf16(Wt - Ws)
// ---------------------------------------------------------------------------
__global__ __launch_bounds__(256) void prep_w(
    const float* __restrict__ Ws, const float* __restrict__ Wt,
    unsigned short* __restrict__ wcat)
{
  const size_t i8 = ((size_t)blockIdx.x * 256 + threadIdx.x) * 8;
  const int t   = (int)(i8 >> 18);          // / (512*512)
  const int rem = (int)(i8 & 262143);
  const int d   = rem >> 9;
  const int c   = rem & 511;
  float4 a0 = *(const float4*)(Ws + i8);
  float4 a1 = *(const float4*)(Ws + i8 + 4);
  float4 b0 = *(const float4*)(Wt + i8);
  float4 b1 = *(const float4*)(Wt + i8 + 4);
  uint4 oa, od;
  oa.x = pk2(a0.x, a0.y); oa.y = pk2(a0.z, a0.w);
  oa.z = pk2(a1.x, a1.y); oa.w = pk2(a1.z, a1.w);
  od.x = pk2(b0.x - a0.x, b0.y - a0.y); od.y = pk2(b0.z - a0.z, b0.w - a0.w);
  od.z = pk2(b1.x - a1.x, b1.y - a1.y); od.w = pk2(b1.z - a1.z, b1.w - a1.w);
  unsigned short* base = wcat + ((size_t)(t * C_N + d)) * KTOT + c;
  *(uint4*)base = oa;
  *(uint4*)(base + C_N) = od;
}

// ---------------------------------------------------------------------------
// prep_a: one pass over x. Acat[t][b][0:512] = bf16(x[b,t,:]),
//         Acat[t][b][512:1024] = bf16(trend[b,t,:]) with trend = u + t*v,
//         u = (S + 18*x0 + 2*x16)/37, v = (x16 - x0)/37.
// ---------------------------------------------------------------------------
__global__ __launch_bounds__(256) void prep_a(
    const float* __restrict__ x, unsigned short* __restrict__ acat)
{
  const int idx = blockIdx.x * 256 + threadIdx.x;   // 4096 * 64 = 262144
  const int b = idx >> 6;
  const int c = (idx & 63) << 3;
  const float* xp = x + (size_t)b * (T_N * C_N) + c;
  float s[8] = {0,0,0,0,0,0,0,0};
  float f0[8], fl[8];
#pragma unroll
  for (int tt = 0; tt < T_N; ++tt){
    float4 w0 = *(const float4*)(xp + (size_t)tt * C_N);
    float4 w1 = *(const float4*)(xp + (size_t)tt * C_N + 4);
    float f[8] = {w0.x, w0.y, w0.z, w0.w, w1.x, w1.y, w1.z, w1.w};
    uint4 o;
    o.x = pk2(f[0],f[1]); o.y = pk2(f[2],f[3]);
    o.z = pk2(f[4],f[5]); o.w = pk2(f[6],f[7]);
    *(uint4*)(acat + ((size_t)tt * B_N + b) * KTOT + c) = o;
    if (tt == 0){
#pragma unroll
      for (int i=0;i<8;++i) f0[i] = f[i];
    }
    if (tt == T_N-1){
#pragma unroll
      for (int i=0;i<8;++i) fl[i] = f[i];
    }
#pragma unroll
    for (int i=0;i<8;++i) s[i] += f[i];
  }
  const float inv = 1.0f / 37.0f;
  float uu[8], vv[8];
#pragma unroll
  for (int i=0;i<8;++i){
    uu[i] = (s[i] + 18.0f * f0[i] + 2.0f * fl[i]) * inv;
    vv[i] = (fl[i] - f0[i]) * inv;
  }
#pragma unroll
  for (int tt = 0; tt < T_N; ++tt){
    const float tfv = (float)tt;
    float tr[8];
#pragma unroll
    for (int i=0;i<8;++i) tr[i] = fmaf(tfv, vv[i], uu[i]);
    uint4 o;
    o.x = pk2(tr[0],tr[1]); o.y = pk2(tr[2],tr[3]);
    o.z = pk2(tr[4],tr[5]); o.w = pk2(tr[6],tr[7]);
    *(uint4*)(acat + ((size_t)tt * B_N + b) * KTOT + C_N + c) = o;
  }
}

// ---------------------------------------------------------------------------
// gemm8p: faithful m201-template port. Per token t:
//   out[:,t,:] = Acat[t] (4096x1024) * Wcat[t]^T (512x1024) + (bs+bt)[t].
// 256x256 tile, BK=64, 8 waves (2M x 4N, wave tile 128x64), 128 KiB LDS.
// 8 phases per iteration (= 2 K-tiles); each phase: {ds_read subtile ||
// 2 global_load_lds || barrier, lgkmcnt(0), setprio(1), 16 MFMA (one
// C-quadrant x K=64), setprio(0), barrier}. Counted vmcnt(2) at phases 4
// and 8 only (never 0 until drain). Quarter-granular staging ring (64-row
// quarters, 1 gll-instr each):
//   p1: B(2i+1).q01 + A(2i+1).q13   p5: A(2i+2).q13
//   p2: B(2i+1).q23                 p6: B(2i+2).q01
//   p3: A(2i+2).q02                 p7: B(2i+2).q23
//   p4: --                          p8: A(2i+3).q02
// Every staged part has >=2 phases of flight and is covered by a counted
// vmcnt before its first read; every WAR has a barrier between last read
// and overwrite. XOR-swizzle: LDS slot s of row r holds global chunk
// s^(r&7); global source pre-swizzled, LDS dest linear (gll16-safe).
// ---------------------------------------------------------------------------
__global__ __launch_bounds__(512, 2) void gemm8p(
    const unsigned short* __restrict__ acat,
    const unsigned short* __restrict__ wcat,
    const float* __restrict__ bs,
    const float* __restrict__ bt,
    float* __restrict__ out)
{
  __shared__ alignas(16) unsigned short A_lds[2][256][64];   // 64 KiB
  __shared__ alignas(16) unsigned short B_lds[2][256][64];   // 64 KiB

  const int tid = threadIdx.x;
  const int bid = blockIdx.x;
  // XCD-contiguous swizzle: 544 blocks = 8 XCDs * 68 (exact -> bijective)
  const int wg = (bid & 7) * 68 + (bid >> 3);
  const int t  = wg >> 5;            // 17 tokens * 32 tiles
  const int mt = (wg >> 1) & 15;     // 16 M-tiles of 256
  const int nt = wg & 1;             // 2 N-tiles of 256
  const int m0 = mt << 8;
  const int n0 = nt << 8;

  const int lane = tid & 63;
  const int wave = tid >> 6;
  const int wr = wave >> 2;          // 0..1 : 128 M rows
  const int wc = wave & 3;           // 0..3 : 64 N cols
  const int lr = lane & 15;
  const int g  = lane >> 4;          // k-chunk group 0..3

  // ---- staging bases: quarter = 64 rows; within a quarter, thread covers
  // row0 = tid>>3 (0..63), 16B chunk cc0 = tid&7. Physical LDS row of
  // quarter q is q*64+row0 -> (row&7) == (row0&7), so one swizzled source
  // column works for all quarters.
  const int row0 = tid >> 3;
  const int cc0  = tid & 7;
  const int cswz = ((cc0 ^ (row0 & 7)) << 3);   // inverse-swizzled src col (ush)
  const unsigned short* gA0 = acat + ((size_t)t * B_N + m0 + row0) * KTOT + cswz;
  const unsigned short* gB0 = wcat + ((size_t)t * C_N + n0 + row0) * KTOT + cswz;
  unsigned short* lA0 = &A_lds[0][0][0] + tid * 8;
  unsigned short* lB0 = &B_lds[0][0][0] + tid * 8;

  // A quarters {mh, mh+2} = the rows read as the mh-half by both wave-rows
  auto stA2 = [&](int bb, int kt, int mh){
    gll16(gA0 + (size_t)kt * 64 + (size_t)(mh * 64) * KTOT,
          lA0 + bb * 16384 + mh * 4096);
    gll16(gA0 + (size_t)kt * 64 + (size_t)(mh * 64 + 128) * KTOT,
          lA0 + bb * 16384 + (mh + 2) * 4096);
  };
  // B half hf = rows hf*128 .. +128 (two quarters)
  auto stB2 = [&](int bb, int kt, int hf){
    gll16(gB0 + (size_t)kt * 64 + (size_t)(hf * 128) * KTOT,
          lB0 + bb * 16384 + hf * 8192);
    gll16(gB0 + (size_t)kt * 64 + (size_t)(hf * 128 + 64) * KTOT,
          lB0 + bb * 16384 + hf * 8192 + 4096);
  };

  // ---- fragment reads (swizzled): frag row = base + 16*frag + lr, so
  // row&7 == lr&7; chunk for k-step ks, group g = (ks*4+g) ^ (lr&7).
  const int sw  = lr & 7;
  const int ca0 = (( g    ) ^ sw) << 3;
  const int ca1 = ((4 | g ) ^ sw) << 3;
  const unsigned short* Arow = &A_lds[0][wr * 128 + lr][0];
  const unsigned short* Brow = &B_lds[0][wc * 64  + lr][0];

  bf16x8 aF[4][2], bF0[2][2], bF1[2][2];
  f32x4 acc[8][4];
#pragma unroll
  for (int i=0;i<8;++i)
#pragma unroll
    for (int j=0;j<4;++j){ f32x4 z = {0.f,0.f,0.f,0.f}; acc[i][j] = z; }

  auto rdA = [&](int bb, int mh){          // 8 ds_read_b128
#pragma unroll
    for (int mi=0;mi<4;++mi){
      const unsigned short* p = Arow + bb * 16384 + mh * 4096 + mi * 1024;
      aF[mi][0] = *(const bf16x8*)(p + ca0);
      aF[mi][1] = *(const bf16x8*)(p + ca1);
    }
  };
  auto rdB = [&](int bb, int nh, bf16x8 (&dst)[2][2]){   // 4 ds_read_b128
#pragma unroll
    for (int ni=0;ni<2;++ni){
      const unsigned short* p = Brow + bb * 16384 + nh * 2048 + ni * 1024;
      dst[ni][0] = *(const bf16x8*)(p + ca0);
      dst[ni][1] = *(const bf16x8*)(p + ca1);
    }
  };
  auto cluster = [&](int mh, int nh, bf16x8 (&bF)[2][2]){  // 16 MFMA
    __builtin_amdgcn_s_setprio(1);
#pragma unroll
    for (int mi=0;mi<4;++mi)
#pragma unroll
      for (int ni=0;ni<2;++ni){
        f32x4* a = &acc[mh*4+mi][nh*2+ni];
        *a = __builtin_amdgcn_mfma_f32_16x16x32_bf16(aF[mi][0], bF[ni][0], *a,0,0,0);
        *a = __builtin_amdgcn_mfma_f32_16x16x32_bf16(aF[mi][1], bF[ni][1], *a,0,0,0);
      }
    __builtin_amdgcn_s_setprio(0);
  };

  // ---- prologue: tiles 0 -> buf0, 1 -> buf1 (16 glls); tile0 landed.
  stA2(0, 0, 0); stA2(0, 0, 1); stB2(0, 0, 0); stB2(0, 0, 1);
  stA2(1, 1, 0); stA2(1, 1, 1); stB2(1, 1, 0); stB2(1, 1, 1);
  VMC(8);
  BAR();

#pragma unroll 1
  for (int i = 0; i < 8; ++i){
    const int s1 = 2*i+1, s2 = 2*i+2, s3 = 2*i+3;
    const bool st1 = (s1 >= 2), st2 = (s2 <= 15), st3 = (s3 <= 15);

    // p1: buf0 quadrant (0,0); stage B(s1).half0 + A(s1).q13
    rdA(0, 0); rdB(0, 0, bF0);
    if (st1){ stB2(1, s1, 0); stA2(1, s1, 1); }
    BAR(); LGKM0();
    cluster(0, 0, bF0);
    BAR();

    // p2: quadrant (0,1); stage B(s1).half1
    rdB(0, 1, bF1);
    if (st1){ stB2(1, s1, 1); }
    BAR(); LGKM0();
    cluster(0, 1, bF1);
    BAR();

    // p3: quadrant (1,0); stage A(s2).q02  (A02 of buf0 last read p1)
    rdA(0, 1);
    if (st2){ stA2(0, s2, 0); }
    BAR(); LGKM0();
    cluster(1, 0, bF0);
    BAR();

    // p4: quadrant (1,1); counted vmcnt: everything up to p2's stages landed
    BAR(); LGKM0();
    cluster(1, 1, bF1);
    if (i < 7) { VMC(2); } else { VMC(0); }
    BAR();

    // p5: buf1 quadrant (0,0); stage A(s2).q13  (A13 of buf0 last read p3)
    rdA(1, 0); rdB(1, 0, bF0);
    if (st2){ stA2(0, s2, 1); }
    BAR(); LGKM0();
    cluster(0, 0, bF0);
    BAR();

    // p6: quadrant (0,1); stage B(s2).half0  (B of buf0 last read p4)
    rdB(1, 1, bF1);
    if (st2){ stB2(0, s2, 0); }
    BAR(); LGKM0();
    cluster(0, 1, bF1);
    BAR();

    // p7: quadrant (1,0); stage B(s2).half1
    rdA(1, 1);
    if (st2){ stB2(0, s2, 1); }
    BAR(); LGKM0();
    cluster(1, 0, bF0);
    BAR();

    // p8: quadrant (1,1); stage A(s3).q02 (A02 of buf1 last read p5);
    //     counted vmcnt: tile s2 (p3,p5,p6,p7) landed for next p1
    if (st3){ stA2(1, s3, 0); }
    BAR(); LGKM0();
    cluster(1, 1, bF1);
    if (i < 7) { VMC(2); } else { VMC(0); }
    BAR();
  }

  // ---- epilogue: bias fused; C/D: col=lane&15 -> n, row=(lane>>4)*4+reg -> m
  float bias[4];
#pragma unroll
  for (int ni=0;ni<4;++ni){
    const size_t bi = (size_t)t * C_N + n0 + wc*64 + ni*16 + lr;
    bias[ni] = bs[bi] + bt[bi];
  }

#pragma unroll
  for (int mi=0;mi<8;++mi){
#pragma unroll
    for (int rr=0;rr<4;++rr){
      const int m = m0 + wr*128 + mi*16 + g*4 + rr;
      float* op = out + ((size_t)m * T_N + t) * C_N + n0 + wc*64 + lr;
#pragma unroll
      for (int ni=0;ni<4;++ni)
        op[ni*16] = acc[mi][ni][rr] + bias[ni];
    }
  }
}

extern "C" void kernel_launch(void* const* d_in, const int* in_sizes, int n_in,
                              void* d_out, int out_size, void* d_ws, size_t ws_size,
                              hipStream_t stream)
{
  const float* x   = (const float*)d_in[0];
  const float* Wsl = (const float*)d_in[1];
  const float* bsl = (const float*)d_in[2];
  const float* Wtr = (const float*)d_in[3];
  const float* btr = (const float*)d_in[4];
  float* out = (float*)d_out;

  const size_t WCAT_BYTES = (size_t)T_N * C_N * KTOT * 2;  // 17,825,792
  char* ws = (char*)d_ws;
  unsigned short* wcat = (unsigned short*)ws;
  unsigned short* acat = (unsigned short*)(ws + WCAT_BYTES);

  prep_w <<<dim3(2176), dim3(256), 0, stream>>>(Wsl, Wtr, wcat);
  prep_a <<<dim3(1024), dim3(256), 0, stream>>>(x, acat);
  gemm8p <<<dim3(544),  dim3(512), 0, stream>>>(acat, wcat, bsl, btr, out);
  (void)in_sizes; (void)n_in; (void)out_size; (void)ws_size;
}